// Round 9
// baseline (318.066 us; speedup 1.0000x reference)
//
#include <hip/hip_runtime.h>

// PointPillarScatter: out[b][c][y][x] = feat[p][c] where coords[p]=(x,y,b), else 0.
//
// v8: FILL-SHAPED WRITER. 7 rounds of evidence: fillBufferAligned writes at
// 6.6-6.7 TB/s; every ownership-partitioned gather (any granule 256B..13KB,
// NT or not, reads separated or not, any occupancy) sits at 3.4-3.7 TB/s.
// v7 proved a globally-synchronized PURE-write phase still caps at 3.7 when
// 256 blocks write 256 distant regions. Last untested difference: the fill's
// grid-stride loop advances ONE contiguous machine-wide write window.
// v8: tiny prep kernels build slot_of (u16 pillar per cell) + featT (feat
// transposed, [c][p]); then a grid-stride writer enumerates output float4s
// in strictly LINEAR address order, sourcing values from L2/L3-resident
// slot_of (1.7 MB) + featT (10 MB). HBM sees ~95% linear write / 5% read.

#define C_CH 64
#define WNB  512      // writer blocks (grid-stride)
#define WBT  256      // writer threads/block (4 waves)

typedef float fvec4 __attribute__((ext_vector_type(4)));

__global__ void build_slots_kernel(const int* __restrict__ coords, int n_pillars,
                                   const int* __restrict__ nx_p,
                                   const int* __restrict__ ny_p,
                                   unsigned short* __restrict__ slot_of) {
    int p = blockIdx.x * blockDim.x + threadIdx.x;
    if (p >= n_pillars) return;
    const int nx = nx_p[0];
    const int ny = ny_p[0];
    const int x = coords[3 * p + 0];
    const int y = coords[3 * p + 1];
    const int b = coords[3 * p + 2];
    const long long m = (long long)b * (long long)(nx * ny) + (long long)y * nx + x;
    slot_of[m] = (unsigned short)p;
}

// featT[c*Ppad + p] = feat[p*64 + c]; 10 MB, stays L2/L3-resident.
__global__ void transpose_feat_kernel(const float* __restrict__ feat,
                                      float* __restrict__ featT,
                                      int n_pillars, int Ppad) {
    const int t = blockIdx.x * blockDim.x + threadIdx.x;
    if (t >= n_pillars * C_CH) return;
    const int p = t >> 6;
    const int c = t & 63;
    featT[(size_t)c * Ppad + p] = feat[t];
}

// Grid-stride writer: output quad index Qj increases linearly with machine
// progress (the fill's pattern). Wave w, lane l, unroll j: quad
// Q = Qb + w*1024 + j*64 + l -> each store instr covers 1 KB contiguous;
// blocks×waves advance one global window per step.
__global__ __launch_bounds__(WBT) void write_sweep_kernel(
    const float* __restrict__ featT, const unsigned short* __restrict__ slot_of,
    const int* __restrict__ nx_p, const int* __restrict__ ny_p,
    float* __restrict__ out, int total_quads, int Ppad, int nb) {
    const int plane = nx_p[0] * ny_p[0];     // uniform
    const int plane_q = plane >> 2;          // quads per (b,c) plane
    const int t = threadIdx.x;
    const int w = t >> 6;
    const int l = t & 63;

    for (int Qb = blockIdx.x * 4096; Qb < total_quads; Qb += nb * 4096) {
        int Q = Qb + w * 1024 + l;           // this lane's j=0 quad
        // Decompose once per step; maintain incrementally across j.
        int bc = (int)((unsigned)Q / (unsigned)plane_q);   // b*64 + c
        int q  = Q - bc * plane_q;           // quad within plane
        int c  = bc & 63;
        int b  = bc >> 6;
        int ci = b * plane + 4 * q;          // cell index of quad
        const float* frow = featT + (size_t)c * Ppad;

#pragma unroll
        for (int j = 0; j < 16; ++j) {
            const int Qj = Q + 64 * j;
            if (Qj < total_quads) {
                const unsigned long long sl =
                    *reinterpret_cast<const unsigned long long*>(slot_of + ci);
                fvec4 v = (fvec4)0.0f;
                if (sl != ~0ull) {           // ~95% of quads fully empty
                    const unsigned s0 = (unsigned)sl & 0xFFFFu;
                    const unsigned s1 = (unsigned)(sl >> 16) & 0xFFFFu;
                    const unsigned s2 = (unsigned)(sl >> 32) & 0xFFFFu;
                    const unsigned s3 = (unsigned)(sl >> 48);
                    if (s0 != 0xFFFFu) v.x = frow[s0];
                    if (s1 != 0xFFFFu) v.y = frow[s1];
                    if (s2 != 0xFFFFu) v.z = frow[s2];
                    if (s3 != 0xFFFFu) v.w = frow[s3];
                }
                reinterpret_cast<fvec4*>(out)[Qj] = v;
            }
            // advance one instruction: quad += 64 (cells += 256)
            q += 64;
            ci += 256;
            if (q >= plane_q) {
                q -= plane_q;
                if (c == 63) { c = 0; ++b; }        // b++: ci already correct
                else         { ++c; ci -= plane; }  // same b: drop one plane
                frow = featT + (size_t)c * Ppad;
            }
        }
    }
}

// Fallback: direct scatter after zeroing the output.
__global__ void direct_scatter_kernel(const float* __restrict__ feat,
                                      const int* __restrict__ coords,
                                      int n_pillars, int C,
                                      const int* __restrict__ nx_p,
                                      const int* __restrict__ ny_p,
                                      float* __restrict__ out) {
    const long long t = (long long)blockIdx.x * blockDim.x + threadIdx.x;
    if (t >= (long long)n_pillars * C) return;
    const int p = (int)(t / C);
    const int c = (int)(t - (long long)p * C);
    const int nx = nx_p[0];
    const int ny = ny_p[0];
    const int x = coords[3 * p + 0];
    const int y = coords[3 * p + 1];
    const int b = coords[3 * p + 2];
    const int plane = nx * ny;
    const size_t o = ((size_t)b * C + c) * (size_t)plane + (size_t)y * nx + x;
    out[o] = feat[(size_t)p * C + c];
}

extern "C" void kernel_launch(void* const* d_in, const int* in_sizes, int n_in,
                              void* d_out, int out_size, void* d_ws, size_t ws_size,
                              hipStream_t stream) {
    const float* feat   = (const float*)d_in[0];
    const int*   coords = (const int*)d_in[1];
    // d_in[2] = batch_size (device scalar, unused on host), d_in[3] = nx,
    // d_in[4] = ny — device-resident scalars, read inside the kernels.
    const int* nx_p = (const int*)d_in[3];
    const int* ny_p = (const int*)d_in[4];
    float* out = (float*)d_out;

    const int n_pillars = in_sizes[1] / 3;
    const int C = in_sizes[0] / n_pillars;
    const int n_map = out_size / C;                 // B * NY * NX
    const int Ppad = (n_pillars + 63) & ~63;

    const size_t slot_bytes  = (size_t)n_map * sizeof(unsigned short);
    const size_t featT_off   = (slot_bytes + 255) & ~(size_t)255;
    const size_t featT_bytes = (size_t)C_CH * Ppad * sizeof(float);
    const size_t need = featT_off + featT_bytes;

    if (C == C_CH && n_pillars < 65535 && ws_size >= need &&
        (out_size % (C_CH * 4)) == 0) {
        unsigned short* slot_of = (unsigned short*)d_ws;
        float* featT = (float*)((char*)d_ws + featT_off);

        // 0xFF bytes -> every slot == 0xFFFF (empty)
        (void)hipMemsetAsync(slot_of, 0xFF, slot_bytes, stream);
        build_slots_kernel<<<(n_pillars + 255) / 256, 256, 0, stream>>>(
            coords, n_pillars, nx_p, ny_p, slot_of);
        transpose_feat_kernel<<<(n_pillars * C_CH + 255) / 256, 256, 0, stream>>>(
            feat, featT, n_pillars, Ppad);

        const int total_quads = (out_size / 4);     // out floats / 4
        write_sweep_kernel<<<WNB, WBT, 0, stream>>>(
            featT, slot_of, nx_p, ny_p, out, total_quads, Ppad, WNB);
    } else {
        (void)hipMemsetAsync(out, 0, (size_t)out_size * sizeof(float), stream);
        const long long total = (long long)n_pillars * C;
        direct_scatter_kernel<<<(unsigned)((total + 255) / 256), 256, 0, stream>>>(
            feat, coords, n_pillars, C, nx_p, ny_p, out);
    }
}